// Round 1
// baseline (148.695 us; speedup 1.0000x reference)
//
#include <hip/hip_runtime.h>
#include <hip/hip_bf16.h>
#include <math.h>

// Weighted-MAE loss: total = sum(w[bin(y)] * |p - y|), count = #valid, out = total/count.
// bin = searchsorted(edge, y, 'right') - 1; valid iff 0 <= bin < n_bins.
// Equivalent select-chain: w = weights[largest j with edge[j] <= y]; valid = (y>=edge[0]) && (y<edge[n_bins]).

#define MAXB 8          // bins held in registers (problem has 7); >MAXB falls back to LDS loop
#define NBLOCKS 1024
#define BLOCK 256

__global__ __launch_bounds__(BLOCK) void wmae_partial(
    const float* __restrict__ y, const float* __restrict__ p,
    const float* __restrict__ weights, const float* __restrict__ edge,
    int n, int n_bins, int n_edges,
    float* __restrict__ psum, float* __restrict__ pcnt)
{
    // generic spillover storage (only read when n_bins > MAXB)
    __shared__ float sh_e[256];
    __shared__ float sh_w[256];
    for (int j = threadIdx.x; j < n_edges && j < 256; j += BLOCK) sh_e[j] = edge[j];
    for (int j = threadIdx.x; j < n_bins  && j < 256; j += BLOCK) sh_w[j] = weights[j];
    __syncthreads();

    // register copies for the fast path (compile-time indexed after unroll)
    float ev[MAXB], wv[MAXB];
#pragma unroll
    for (int j = 0; j < MAXB; ++j) {
        ev[j] = (j < n_edges) ? edge[j] : 3.4e38f;
        wv[j] = (j < n_bins)  ? weights[j] : 0.0f;
    }
    const float e0 = edge[0];
    // upper validity bound: bin < n_bins  <=>  y < edge[n_bins] (when it exists)
    const float eup = (n_bins < n_edges) ? edge[n_bins] : 3.4e38f;

    float sum = 0.0f;
    int   cnt = 0;

    auto proc = [&](float yy, float pp) {
        float w = 0.0f;
#pragma unroll
        for (int j = 0; j < MAXB; ++j) {
            if (j < n_bins) w = (yy >= ev[j]) ? wv[j] : w;
        }
        if (n_bins > MAXB) {                      // uniform branch; not taken here
            for (int j = MAXB; j < n_bins; ++j)
                w = (yy >= sh_e[j]) ? sh_w[j] : w;
        }
        bool valid = (yy >= e0) && (yy < eup);
        sum += (valid ? w : 0.0f) * fabsf(pp - yy);
        cnt += valid ? 1 : 0;
    };

    const int tid    = blockIdx.x * BLOCK + threadIdx.x;
    const int stride = gridDim.x * BLOCK;
    const int n4     = n >> 2;
    const float4* y4 = (const float4*)y;
    const float4* p4 = (const float4*)p;

    for (int i = tid; i < n4; i += stride) {
        float4 yv = y4[i];
        float4 pv = p4[i];
        proc(yv.x, pv.x);
        proc(yv.y, pv.y);
        proc(yv.z, pv.z);
        proc(yv.w, pv.w);
    }
    // scalar tail
    for (int i = (n4 << 2) + tid; i < n; i += stride) proc(y[i], p[i]);

    // wave (64-lane) reduce
#pragma unroll
    for (int off = 32; off > 0; off >>= 1) {
        sum += __shfl_down(sum, off, 64);
        cnt += __shfl_down(cnt, off, 64);
    }
    __shared__ float wsum[BLOCK / 64];
    __shared__ int   wcnt[BLOCK / 64];
    const int wave = threadIdx.x >> 6;
    const int lane = threadIdx.x & 63;
    if (lane == 0) { wsum[wave] = sum; wcnt[wave] = cnt; }
    __syncthreads();
    if (threadIdx.x == 0) {
        float s = 0.0f; int c = 0;
#pragma unroll
        for (int w2 = 0; w2 < BLOCK / 64; ++w2) { s += wsum[w2]; c += wcnt[w2]; }
        psum[blockIdx.x] = s;
        pcnt[blockIdx.x] = (float)c;   // counts are integers < 2^24: exact in fp32
    }
}

__global__ __launch_bounds__(BLOCK) void wmae_final(
    const float* __restrict__ psum, const float* __restrict__ pcnt,
    int nparts, float* __restrict__ out)
{
    float s = 0.0f, c = 0.0f;
    for (int i = threadIdx.x; i < nparts; i += BLOCK) { s += psum[i]; c += pcnt[i]; }
#pragma unroll
    for (int off = 32; off > 0; off >>= 1) {
        s += __shfl_down(s, off, 64);
        c += __shfl_down(c, off, 64);
    }
    __shared__ float wsum[BLOCK / 64];
    __shared__ float wcnt[BLOCK / 64];
    const int wave = threadIdx.x >> 6;
    const int lane = threadIdx.x & 63;
    if (lane == 0) { wsum[wave] = s; wcnt[wave] = c; }
    __syncthreads();
    if (threadIdx.x == 0) {
        float S = 0.0f, C = 0.0f;
#pragma unroll
        for (int w2 = 0; w2 < BLOCK / 64; ++w2) { S += wsum[w2]; C += wcnt[w2]; }
        out[0] = S / C;
    }
}

extern "C" void kernel_launch(void* const* d_in, const int* in_sizes, int n_in,
                              void* d_out, int out_size, void* d_ws, size_t ws_size,
                              hipStream_t stream) {
    const float* y       = (const float*)d_in[0];
    const float* p       = (const float*)d_in[1];
    const float* weights = (const float*)d_in[2];
    const float* edge    = (const float*)d_in[3];
    const int n       = in_sizes[0];
    const int n_bins  = in_sizes[2];
    const int n_edges = in_sizes[3];

    float* psum = (float*)d_ws;            // NBLOCKS floats
    float* pcnt = psum + NBLOCKS;          // NBLOCKS floats
    float* out  = (float*)d_out;

    wmae_partial<<<NBLOCKS, BLOCK, 0, stream>>>(y, p, weights, edge,
                                                n, n_bins, n_edges, psum, pcnt);
    wmae_final<<<1, BLOCK, 0, stream>>>(psum, pcnt, NBLOCKS, out);
}